// Round 1
// baseline (521.402 us; speedup 1.0000x reference)
//
#include <hip/hip_runtime.h>

#define NDIM 64
#define KPOS 32
#define KNEG 64

// ---------------- Kernel 1: Z = sigmoid(P), L_deg = mean((Z@W_d - deg)^2) ----
__global__ __launch_bounds__(256) void pe_sig_deg_kernel(
    const float* __restrict__ P,
    const float* __restrict__ Wd,
    const float* __restrict__ deg,
    float* __restrict__ Z,
    float* __restrict__ out,
    int N) {
  const int lane = threadIdx.x & 63;
  const int wid  = threadIdx.x >> 6;
  const int nwaves = (gridDim.x * blockDim.x) >> 6;
  int gw = (blockIdx.x * blockDim.x + threadIdx.x) >> 6;

  const float wd = Wd[lane];
  float acc = 0.f;
  for (int i = gw; i < N; i += nwaves) {
    float p = P[i * NDIM + lane];
    float z = 1.f / (1.f + __expf(-p));
    Z[i * NDIM + lane] = z;
    float dot = z * wd;
    #pragma unroll
    for (int off = 32; off; off >>= 1) dot += __shfl_xor(dot, off);
    float d = dot - deg[i];
    acc += d * d;   // uniform across lanes
  }
  __shared__ float sacc[4];
  if (lane == 0) sacc[wid] = acc;
  __syncthreads();
  if (threadIdx.x == 0) {
    float s = (sacc[0] + sacc[1]) + (sacc[2] + sacc[3]);
    atomicAdd(out + 2, s * (1.0f / (float)N));
  }
}

// ---------------- Kernel 2: the two contrast losses -------------------------
__device__ __forceinline__ float contrast_node(
    const float* __restrict__ Z, float zi, int i,
    const int* __restrict__ pos_idx, const int* __restrict__ neg_idx,
    int lane) {
  // positive: only need total sum over (k, d)
  float accp = 0.f;
  const int* pr = pos_idx + i * KPOS;
  for (int k = 0; k < KPOS; ++k) {
    int j = pr[k];                         // wave-uniform load
    accp += fabsf(zi - Z[j * NDIM + lane]);
  }
  #pragma unroll
  for (int off = 32; off; off >>= 1) accp += __shfl_xor(accp, off);

  // negative: per-neighbor sums, parked into lane k, then LSE over lanes
  float hk = 0.f;
  const int* nr = neg_idx + i * KNEG;
  for (int k = 0; k < KNEG; ++k) {
    int j = nr[k];
    float v = fabsf(zi - Z[j * NDIM + lane]);
    #pragma unroll
    for (int off = 32; off; off >>= 1) v += __shfl_xor(v, off);
    if (lane == k) hk = v;                 // v uniform after full butterfly
  }
  float m = hk;
  #pragma unroll
  for (int off = 32; off; off >>= 1) m = fmaxf(m, __shfl_xor(m, off));
  float e = __expf(hk - m);
  #pragma unroll
  for (int off = 32; off; off >>= 1) e += __shfl_xor(e, off);
  float lse = m + __logf(e);

  // contribution to  -sum_i (mean_p - lse)  ==  sum_i (lse - mean_p)
  return lse - accp * (1.f / (float)KPOS);
}

__global__ __launch_bounds__(256) void pe_contrast_kernel(
    const float* __restrict__ Z,
    const int* __restrict__ pos_idx,
    const int* __restrict__ neg_idx,
    const int* __restrict__ dpos_idx,
    const int* __restrict__ dneg_idx,
    float* __restrict__ out,
    int N) {
  const int lane = threadIdx.x & 63;
  const int wid  = threadIdx.x >> 6;
  const int nwaves = (gridDim.x * blockDim.x) >> 6;
  int gw = (blockIdx.x * blockDim.x + threadIdx.x) >> 6;

  float l_adj = 0.f, l_dd = 0.f;
  for (int i = gw; i < N; i += nwaves) {
    const float zi = Z[i * NDIM + lane];
    l_adj += contrast_node(Z, zi, i, pos_idx, neg_idx, lane);
    l_dd  += contrast_node(Z, zi, i, dpos_idx, dneg_idx, lane);
  }

  __shared__ float s1[4], s2[4];
  if (lane == 0) { s1[wid] = l_adj; s2[wid] = l_dd; }
  __syncthreads();
  if (threadIdx.x == 0) {
    atomicAdd(out + 0, (s1[0] + s1[1]) + (s1[2] + s1[3]));
    atomicAdd(out + 1, (s2[0] + s2[1]) + (s2[2] + s2[3]));
  }
}

// ---------------- launch ----------------------------------------------------
extern "C" void kernel_launch(void* const* d_in, const int* in_sizes, int n_in,
                              void* d_out, int out_size, void* d_ws, size_t ws_size,
                              hipStream_t stream) {
  const float* P       = (const float*)d_in[0];
  const float* Wd      = (const float*)d_in[1];
  const float* deg     = (const float*)d_in[2];
  const int*   pos_idx = (const int*)d_in[3];
  const int*   neg_idx = (const int*)d_in[4];
  const int*   dpos    = (const int*)d_in[5];
  const int*   dneg    = (const int*)d_in[6];
  float* out = (float*)d_out;

  const int N = in_sizes[2];          // deg_vec has N elements
  float* Z = (float*)d_ws;            // N * 64 floats = 12.8 MB

  hipMemsetAsync(out, 0, (size_t)out_size * sizeof(float), stream);

  pe_sig_deg_kernel<<<512, 256, 0, stream>>>(P, Wd, deg, Z, out, N);
  pe_contrast_kernel<<<2048, 256, 0, stream>>>(Z, pos_idx, neg_idx, dpos, dneg, out, N);
}

// Round 2
// 150.005 us; speedup vs baseline: 3.4759x; 3.4759x over previous
//
#include <hip/hip_runtime.h>
#include <hip/hip_fp16.h>

#define NDIM 64
#define KPOS 32
#define KNEG 64

union F4H2 { float4 f; __half2 h[4]; };

// ---------------- Kernel 1: Zh = half(sigmoid(P)), L_deg = MSE(Z@W_d, deg) --
__global__ __launch_bounds__(256) void pe_sig_deg_kernel(
    const float* __restrict__ P,
    const float* __restrict__ Wd,
    const float* __restrict__ deg,
    __half* __restrict__ Zh,
    float* __restrict__ out,
    int N) {
  const int lane = threadIdx.x & 63;
  const int wid  = threadIdx.x >> 6;
  const int nwaves = (gridDim.x * blockDim.x) >> 6;
  int gw = (blockIdx.x * blockDim.x + threadIdx.x) >> 6;

  const float wd = Wd[lane];
  float acc = 0.f;
  for (int i = gw; i < N; i += nwaves) {
    float p = P[(size_t)i * NDIM + lane];
    float z = 1.f / (1.f + __expf(-p));
    Zh[(size_t)i * NDIM + lane] = __float2half_rn(z);
    float dot = z * wd;                       // f32 path for L_deg
    #pragma unroll
    for (int off = 32; off; off >>= 1) dot += __shfl_xor(dot, off);
    float d = dot - deg[i];
    acc += d * d;                             // uniform across lanes
  }
  __shared__ float sacc[4];
  if (lane == 0) sacc[wid] = acc;
  __syncthreads();
  if (threadIdx.x == 0) {
    atomicAdd(out + 2, (sacc[0] + sacc[1] + sacc[2] + sacc[3]) * (1.0f / (float)N));
  }
}

// ---- per-(lane, neighbor) partial Hamming: this lane's 16 dims of row j ----
__device__ __forceinline__ float neigh_h(const __half* __restrict__ Zh, int j,
                                         const F4H2& z0, const F4H2& z1, int c) {
  const float4* r = (const float4*)(Zh + (size_t)j * NDIM);
  F4H2 w0, w1;
  w0.f = r[c];       // halves [8c, 8c+8)
  w1.f = r[4 + c];   // halves [32+8c, 32+8c+8)
  __half2 a = __habs2(__hsub2(w0.h[0], z0.h[0]));
  a = __hadd2(a, __habs2(__hsub2(w0.h[1], z0.h[1])));
  a = __hadd2(a, __habs2(__hsub2(w0.h[2], z0.h[2])));
  a = __hadd2(a, __habs2(__hsub2(w0.h[3], z0.h[3])));
  __half2 b = __habs2(__hsub2(w1.h[0], z1.h[0]));
  b = __hadd2(b, __habs2(__hsub2(w1.h[1], z1.h[1])));
  b = __hadd2(b, __habs2(__hsub2(w1.h[2], z1.h[2])));
  b = __hadd2(b, __habs2(__hsub2(w1.h[3], z1.h[3])));
  a = __hadd2(a, b);
  return __low2float(a) + __high2float(a);
}

// ---- one node's (lse_neg - mean_pos) contribution -------------------------
__device__ __forceinline__ float contrast_node(
    const __half* __restrict__ Zh,
    const F4H2& z0, const F4H2& z1,
    const int* __restrict__ pr,   // KPOS indices
    const int* __restrict__ nr,   // KNEG indices
    int q, int c) {
  // ---- negatives: 4 groups of 16 neighbors (quad q owns one per group) ----
  float hk0, hk1, hk2, hk3;
  {
    float h = neigh_h(Zh, nr[q],      z0, z1, c);
    h += __shfl_xor(h, 1); h += __shfl_xor(h, 2); hk0 = h;
  }
  {
    float h = neigh_h(Zh, nr[16 + q], z0, z1, c);
    h += __shfl_xor(h, 1); h += __shfl_xor(h, 2); hk1 = h;
  }
  {
    float h = neigh_h(Zh, nr[32 + q], z0, z1, c);
    h += __shfl_xor(h, 1); h += __shfl_xor(h, 2); hk2 = h;
  }
  {
    float h = neigh_h(Zh, nr[48 + q], z0, z1, c);
    h += __shfl_xor(h, 1); h += __shfl_xor(h, 2); hk3 = h;
  }
  float m = fmaxf(fmaxf(hk0, hk1), fmaxf(hk2, hk3));
  #pragma unroll
  for (int off = 4; off < 64; off <<= 1) m = fmaxf(m, __shfl_xor(m, off));
  float e = __expf(hk0 - m) + __expf(hk1 - m) + __expf(hk2 - m) + __expf(hk3 - m);
  #pragma unroll
  for (int off = 4; off < 64; off <<= 1) e += __shfl_xor(e, off);
  float lse = m + __logf(e);   // cross-quad sum counts each neighbor once

  // ---- positives: 2 groups; only the total sum is needed ------------------
  float s = neigh_h(Zh, pr[q], z0, z1, c) + neigh_h(Zh, pr[16 + q], z0, z1, c);
  #pragma unroll
  for (int off = 1; off < 64; off <<= 1) s += __shfl_xor(s, off);  // all partials distinct

  return lse - s * (1.0f / (float)KPOS);
}

// ---------------- Kernel 2: both contrast losses ---------------------------
__global__ __launch_bounds__(256) void pe_contrast_kernel(
    const __half* __restrict__ Zh,
    const int* __restrict__ pos_idx,
    const int* __restrict__ neg_idx,
    const int* __restrict__ dpos_idx,
    const int* __restrict__ dneg_idx,
    float* __restrict__ out,
    int N) {
  const int lane = threadIdx.x & 63;
  const int q = lane >> 2, c = lane & 3;
  const int wid  = threadIdx.x >> 6;
  const int nwaves = (gridDim.x * blockDim.x) >> 6;
  int gw = (blockIdx.x * blockDim.x + threadIdx.x) >> 6;

  float l_adj = 0.f, l_dd = 0.f;
  for (int i = gw; i < N; i += nwaves) {
    const float4* zr = (const float4*)(Zh + (size_t)i * NDIM);
    F4H2 z0, z1;
    z0.f = zr[c];
    z1.f = zr[4 + c];
    l_adj += contrast_node(Zh, z0, z1,
                           pos_idx + (size_t)i * KPOS, neg_idx + (size_t)i * KNEG, q, c);
    l_dd  += contrast_node(Zh, z0, z1,
                           dpos_idx + (size_t)i * KPOS, dneg_idx + (size_t)i * KNEG, q, c);
  }

  __shared__ float s1[4], s2[4];
  if (lane == 0) { s1[wid] = l_adj; s2[wid] = l_dd; }
  __syncthreads();
  if (threadIdx.x == 0) {
    atomicAdd(out + 0, s1[0] + s1[1] + s1[2] + s1[3]);
    atomicAdd(out + 1, s2[0] + s2[1] + s2[2] + s2[3]);
  }
}

// ---------------- launch ----------------------------------------------------
extern "C" void kernel_launch(void* const* d_in, const int* in_sizes, int n_in,
                              void* d_out, int out_size, void* d_ws, size_t ws_size,
                              hipStream_t stream) {
  const float* P       = (const float*)d_in[0];
  const float* Wd      = (const float*)d_in[1];
  const float* deg     = (const float*)d_in[2];
  const int*   pos_idx = (const int*)d_in[3];
  const int*   neg_idx = (const int*)d_in[4];
  const int*   dpos    = (const int*)d_in[5];
  const int*   dneg    = (const int*)d_in[6];
  float* out = (float*)d_out;

  const int N = in_sizes[2];           // deg_vec has N elements
  __half* Zh = (__half*)d_ws;          // N * 64 halves = 6.4 MB

  hipMemsetAsync(out, 0, (size_t)out_size * sizeof(float), stream);

  pe_sig_deg_kernel<<<512, 256, 0, stream>>>(P, Wd, deg, Zh, out, N);
  pe_contrast_kernel<<<2048, 256, 0, stream>>>(Zh, pos_idx, neg_idx, dpos, dneg, out, N);
}

// Round 3
// 101.701 us; speedup vs baseline: 5.1268x; 1.4750x over previous
//
#include <hip/hip_runtime.h>
#include <stdint.h>

#define NDIM 64
#define KPOS 32
#define KNEG 64

// ---------------- Kernel 1: Zq = u8(sigmoid(P)*255), L_deg = MSE(Z@W_d,deg) -
__global__ __launch_bounds__(256) void pe_sig_deg_kernel(
    const float* __restrict__ P,
    const float* __restrict__ Wd,
    const float* __restrict__ deg,
    uint8_t* __restrict__ Zq,
    float* __restrict__ out,
    int N) {
  const int lane = threadIdx.x & 63;
  const int wid  = threadIdx.x >> 6;
  const int nwaves = (gridDim.x * blockDim.x) >> 6;
  int gw = (blockIdx.x * blockDim.x + threadIdx.x) >> 6;

  const float wd = Wd[lane];
  float acc = 0.f;
  for (int i = gw; i < N; i += nwaves) {
    float p = P[(size_t)i * NDIM + lane];
    float z = 1.f / (1.f + __expf(-p));
    Zq[(size_t)i * NDIM + lane] = (uint8_t)(z * 255.f + 0.5f);  // z<1 -> <=255
    float dot = z * wd;                        // exact f32 path for L_deg
    #pragma unroll
    for (int off = 32; off; off >>= 1) dot += __shfl_xor(dot, off);
    float d = dot - deg[i];
    acc += d * d;                              // uniform across lanes
  }
  __shared__ float sacc[4];
  if (lane == 0) sacc[wid] = acc;
  __syncthreads();
  if (threadIdx.x == 0) {
    atomicAdd(out + 2, (sacc[0] + sacc[1] + sacc[2] + sacc[3]) * (1.0f / (float)N));
  }
}

// ---------------- u8 SAD helpers -------------------------------------------
__device__ __forceinline__ unsigned sad16(uint4 a, uint4 b, unsigned acc) {
  acc = __builtin_amdgcn_sad_u8(a.x, b.x, acc);
  acc = __builtin_amdgcn_sad_u8(a.y, b.y, acc);
  acc = __builtin_amdgcn_sad_u8(a.z, b.z, acc);
  acc = __builtin_amdgcn_sad_u8(a.w, b.w, acc);
  return acc;
}

// one contrast list pair for node i; returns lse contribution, accumulates
// raw integer pos-SAD into *posacc (scaled/averaged once at kernel end).
__device__ __forceinline__ float contrast_u8(
    const uint8_t* __restrict__ Zq, uint4 zi,
    int p0, int p1, int n0, int n1, int n2, int n3,
    int c, unsigned* posacc) {
  const size_t off = (size_t)c * 16;
  const uint4 rp0 = *(const uint4*)(Zq + (size_t)p0 * NDIM + off);
  const uint4 rp1 = *(const uint4*)(Zq + (size_t)p1 * NDIM + off);
  const uint4 rn0 = *(const uint4*)(Zq + (size_t)n0 * NDIM + off);
  const uint4 rn1 = *(const uint4*)(Zq + (size_t)n1 * NDIM + off);
  const uint4 rn2 = *(const uint4*)(Zq + (size_t)n2 * NDIM + off);
  const uint4 rn3 = *(const uint4*)(Zq + (size_t)n3 * NDIM + off);

  *posacc = sad16(rp0, zi, sad16(rp1, zi, *posacc));

  int h0 = (int)sad16(rn0, zi, 0u);
  int h1 = (int)sad16(rn1, zi, 0u);
  int h2 = (int)sad16(rn2, zi, 0u);
  int h3 = (int)sad16(rn3, zi, 0u);
  // quad-reduce: full per-neighbor Hamming (integer, exact)
  h0 += __shfl_xor(h0, 1); h0 += __shfl_xor(h0, 2);
  h1 += __shfl_xor(h1, 1); h1 += __shfl_xor(h1, 2);
  h2 += __shfl_xor(h2, 1); h2 += __shfl_xor(h2, 2);
  h3 += __shfl_xor(h3, 1); h3 += __shfl_xor(h3, 2);

  int m = max(max(h0, h1), max(h2, h3));
  #pragma unroll
  for (int o = 4; o < 64; o <<= 1) m = max(m, __shfl_xor(m, o));

  const float s = 1.4426950408889634f / 255.f;  // log2(e)/255
  float e = exp2f((float)(h0 - m) * s) + exp2f((float)(h1 - m) * s) +
            exp2f((float)(h2 - m) * s) + exp2f((float)(h3 - m) * s);
  #pragma unroll
  for (int o = 4; o < 64; o <<= 1) e += __shfl_xor(e, o);

  return (float)m * (1.f / 255.f) + __logf(e);   // uniform across lanes
}

struct Idx { int p0, p1, n0, n1, n2, n3, q0, q1, m0, m1, m2, m3; };

__device__ __forceinline__ Idx load_idx(
    const int* __restrict__ pos, const int* __restrict__ neg,
    const int* __restrict__ dpos, const int* __restrict__ dneg, int i, int q) {
  Idx d;
  const int* pr = pos  + (size_t)i * KPOS;
  const int* nr = neg  + (size_t)i * KNEG;
  const int* qr = dpos + (size_t)i * KPOS;
  const int* mr = dneg + (size_t)i * KNEG;
  d.p0 = pr[q]; d.p1 = pr[16 + q];
  d.n0 = nr[q]; d.n1 = nr[16 + q]; d.n2 = nr[32 + q]; d.n3 = nr[48 + q];
  d.q0 = qr[q]; d.q1 = qr[16 + q];
  d.m0 = mr[q]; d.m1 = mr[16 + q]; d.m2 = mr[32 + q]; d.m3 = mr[48 + q];
  return d;
}

// ---------------- Kernel 2: both contrast losses ---------------------------
__global__ __launch_bounds__(256) void pe_contrast_kernel(
    const uint8_t* __restrict__ Zq,
    const int* __restrict__ pos_idx,
    const int* __restrict__ neg_idx,
    const int* __restrict__ dpos_idx,
    const int* __restrict__ dneg_idx,
    float* __restrict__ out,
    int N) {
  const int lane = threadIdx.x & 63;
  const int q = lane >> 2, c = lane & 3;
  const int wid  = threadIdx.x >> 6;
  const int nwaves = (gridDim.x * blockDim.x) >> 6;
  const int gw = (blockIdx.x * blockDim.x + threadIdx.x) >> 6;

  float l1 = 0.f, l2 = 0.f;
  unsigned pa1 = 0u, pa2 = 0u;

  int i = gw;
  Idx cur;
  if (i < N) cur = load_idx(pos_idx, neg_idx, dpos_idx, dneg_idx, i, q);
  while (i < N) {
    const int inext = i + nwaves;
    Idx nxt = cur;
    if (inext < N) nxt = load_idx(pos_idx, neg_idx, dpos_idx, dneg_idx, inext, q);

    const uint4 zi = *(const uint4*)(Zq + (size_t)i * NDIM + (size_t)c * 16);
    l1 += contrast_u8(Zq, zi, cur.p0, cur.p1, cur.n0, cur.n1, cur.n2, cur.n3, c, &pa1);
    l2 += contrast_u8(Zq, zi, cur.q0, cur.q1, cur.m0, cur.m1, cur.m2, cur.m3, c, &pa2);

    i = inext;
    cur = nxt;
  }

  // wave-reduce the integer positive accumulators (per-lane distinct)
  int p1s = (int)pa1, p2s = (int)pa2;
  #pragma unroll
  for (int o = 1; o < 64; o <<= 1) { p1s += __shfl_xor(p1s, o); p2s += __shfl_xor(p2s, o); }

  const float pscale = 1.f / (255.f * (float)KPOS);
  const float c1 = l1 - (float)p1s * pscale;   // sum_i (lse - mean_pos)
  const float c2 = l2 - (float)p2s * pscale;

  __shared__ float s1[4], s2[4];
  if (lane == 0) { s1[wid] = c1; s2[wid] = c2; }
  __syncthreads();
  if (threadIdx.x == 0) {
    atomicAdd(out + 0, s1[0] + s1[1] + s1[2] + s1[3]);
    atomicAdd(out + 1, s2[0] + s2[1] + s2[2] + s2[3]);
  }
}

// ---------------- launch ----------------------------------------------------
extern "C" void kernel_launch(void* const* d_in, const int* in_sizes, int n_in,
                              void* d_out, int out_size, void* d_ws, size_t ws_size,
                              hipStream_t stream) {
  const float* P       = (const float*)d_in[0];
  const float* Wd      = (const float*)d_in[1];
  const float* deg     = (const float*)d_in[2];
  const int*   pos_idx = (const int*)d_in[3];
  const int*   neg_idx = (const int*)d_in[4];
  const int*   dpos    = (const int*)d_in[5];
  const int*   dneg    = (const int*)d_in[6];
  float* out = (float*)d_out;

  const int N = in_sizes[2];            // deg_vec has N elements
  uint8_t* Zq = (uint8_t*)d_ws;         // N * 64 bytes = 3.2 MB

  hipMemsetAsync(out, 0, (size_t)out_size * sizeof(float), stream);

  pe_sig_deg_kernel<<<1024, 256, 0, stream>>>(P, Wd, deg, Zq, out, N);
  pe_contrast_kernel<<<2048, 256, 0, stream>>>(Zq, pos_idx, neg_idx, dpos, dneg, out, N);
}